// Round 3
// baseline (173.060 us; speedup 1.0000x reference)
//
#include <hip/hip_runtime.h>

// out[b, c, w, f] = X[b, c, f*HOP + w]  == transpose of contiguous X chunks.
// B=16, C=2, T=262144, WINDOW=1024, HOP=256, NF=1021
#define WINDOW_SZ 1024
#define HOP_SZ    256
#define NFRAMES   1021
#define T_LEN     262144

#define FT 256     // frames per tile
#define WT 16      // window rows per tile
#define LDS_S 261  // row stride in words; ==1 (mod 4) => global-aligned f is also LDS-16B-aligned

__global__ __launch_bounds__(256)
void frame_transpose2(const float* __restrict__ X, float* __restrict__ out) {
    __shared__ __align__(16) float lds[WT * LDS_S];  // lds[w][f], 16.7 KB

    const int tid  = threadIdx.x;
    const int f0   = blockIdx.x * FT;
    const int w0   = blockIdx.y * WT;
    const int bc   = blockIdx.z;
    const int flim = min(FT, NFRAMES - f0);   // 256, or 253 in the last f-tile

    const float* Xb = X + (size_t)bc * T_LEN;

    // ---- load phase: float4 reads (per instr: 16 f-rows x 64B contiguous),
    //      scatter into lds[w][f]. Banks (5*(4q+k)+f) mod 32 -> <=3-way, ~free.
    {
        const int q  = tid & 3;    // w quad: covers w = 4q..4q+3
        const int fr = tid >> 2;   // 0..63
#pragma unroll
        for (int p = 0; p < 4; ++p) {
            const int f = fr + 64 * p;   // local frame index
            if (f < flim) {
                const float4 v = *(const float4*)(Xb + (size_t)(f0 + f) * HOP_SZ + w0 + 4 * q);
                float* dst = &lds[(4 * q) * LDS_S + f];
                dst[0 * LDS_S] = v.x;
                dst[1 * LDS_S] = v.y;
                dst[2 * LDS_S] = v.z;
                dst[3 * LDS_S] = v.w;
            }
        }
    }
    __syncthreads();

    // ---- store phase: wave = ONE output row per iter.
    //      Alignment phase a = w mod 4 is wave-uniform -> branchless peel.
    //      Bulk: ds_read_b128 (conflict-free: start banks 4c mod 32, 8 disjoint
    //      spans) + global dwordx4 (1 KB contiguous per wave-instr, 16B aligned).
    {
        const int lane = tid & 63;
        const int wv   = tid >> 6;
#pragma unroll
        for (int i = 0; i < 4; ++i) {
            const int wl = wv * 4 + i;           // local row 0..15
            const int wg = w0 + wl;              // global w
            const int p  = (4 - (wg & 3)) & 3;   // first aligned local f
            float* orow = out + ((size_t)bc * WINDOW_SZ + wg) * (size_t)NFRAMES + f0;
            const float* lrow = &lds[wl * LDS_S];

            // bulk: lane stores f = p+4*lane .. +3
            const int fv = p + 4 * lane;
            if (fv + 4 <= flim) {
                // wl*261 + p == 0 (mod 4)  -> 16B-aligned LDS read
                const float4 v = *(const float4*)(lrow + fv);
                *(float4*)(orow + fv) = v;   // global index == 0 (mod 4)
            }
            // cleanup: head (p floats) + tail ((flim-p)&3 floats), <=6 lanes
            const int nt = (flim - p) & 3;
            const int ts = flim - nt;
            int fs = -1;
            if (lane < p) fs = lane;
            else if (lane < p + nt) fs = ts + (lane - p);
            if (fs >= 0) orow[fs] = lrow[fs];
        }
    }
}

extern "C" void kernel_launch(void* const* d_in, const int* in_sizes, int n_in,
                              void* d_out, int out_size, void* d_ws, size_t ws_size,
                              hipStream_t stream) {
    const float* X = (const float*)d_in[0];
    float* out = (float*)d_out;

    dim3 block(256, 1, 1);
    dim3 grid((NFRAMES + FT - 1) / FT,   // 4 frame tiles
              WINDOW_SZ / WT,            // 64 window tiles
              32);                       // b*c slabs
    frame_transpose2<<<grid, block, 0, stream>>>(X, out);
}